// Round 1
// baseline (1153.583 us; speedup 1.0000x reference)
//
#include <hip/hip_runtime.h>

// 3x3 stride-1 VALID conv, NCHW fp32 in/out, bf16 MFMA implicit GEMM.
// N=16, Cin=Cout=32, 512x512 -> 510x510.
// Mapping: D[m=co][n=pixel], K=ci (32, one MFMA K), 9 taps accumulate.
// A = weights (18 frags preloaded in VGPRs), B = X tile from LDS [pixel][ci].

namespace {
constexpr int NI    = 16;
constexpr int C_IN  = 32;
constexpr int HI    = 512;
constexpr int WI    = 512;
constexpr int C_OUT = 32;
constexpr int HO    = 510;
constexpr int WO    = 510;

constexpr int RT    = 6;        // output rows per block
constexpr int PT    = 64;       // output x-pixels per block (4 waves x 16)
constexpr int XROWS = RT + 2;   // 8 staged input rows
constexpr int XCOLS = PT + 2;   // 66 staged input cols
constexpr int PSTR  = 40;       // shorts per pixel in LDS (32 ci + 8 pad -> 80B stride)
}

typedef __attribute__((ext_vector_type(4))) float  floatx4;
typedef __attribute__((ext_vector_type(2))) float  floatx2;
typedef __attribute__((ext_vector_type(8))) __bf16 bf16x8;

__device__ __forceinline__ unsigned short f2bf(float f) {
  union { float f; unsigned u; } v; v.f = f;
  unsigned r = v.u + 0x7fffu + ((v.u >> 16) & 1u);   // RNE
  return (unsigned short)(r >> 16);
}

__global__ __launch_bounds__(256, 3)
void conv3x3_mfma(const float* __restrict__ x, const float* __restrict__ w,
                  const float* __restrict__ bias, float* __restrict__ out) {
  __shared__ unsigned short lds[XROWS * XCOLS * PSTR];  // 42240 B; weights borrow first 18432 B

  const int t    = threadIdx.x;
  const int lane = t & 63;
  const int wv   = t >> 6;
  const int quad = lane >> 4;
  const int l16  = lane & 15;

  const int x0 = blockIdx.x * PT;
  const int y0 = blockIdx.y * RT;
  const int n  = blockIdx.z;

  // ---- stage weights into LDS in A-fragment order [tap][coHalf][co16][ci32]
  for (int e = t; e < C_OUT * C_IN * 9; e += 256) {
    const int co  = e / 288;          // w is [co][ci][ky][kx]
    const int rem = e - co * 288;
    const int ci  = rem / 9;
    const int tap = rem - ci * 9;     // ky*3+kx
    lds[((tap * 2 + (co >> 4)) * 16 + (co & 15)) * 32 + ci] = f2bf(w[e]);
  }
  __syncthreads();

  // ---- A fragments: lane holds W[co = h*16 + l16][ci = quad*8 + j] for each tap
  bf16x8 afrag[9][2];
#pragma unroll
  for (int tap = 0; tap < 9; ++tap)
#pragma unroll
    for (int h = 0; h < 2; ++h)
      afrag[tap][h] = *reinterpret_cast<const bf16x8*>(
          &lds[((tap * 2 + h) * 16 + l16) * 32 + quad * 8]);

  // bias per accumulator register: D row (m=co) = quad*4 + r (+16 for second half)
  float b0[4], b1[4];
#pragma unroll
  for (int r = 0; r < 4; ++r) {
    b0[r] = bias[quad * 4 + r];
    b1[r] = bias[quad * 4 + r + 16];
  }
  __syncthreads();  // protect LDS reuse (weights region overwritten by X tile)

  // ---- stage X tile bf16: rows y0..y0+7, cols x0..x0+65, layout [row*66+xx][ci]
  for (int e = t; e < C_IN * XROWS * 33; e += 256) {   // float2 units, 33 iters/thread
    const int ci  = e / 264;
    const int rem = e - ci * 264;
    const int r   = rem / 33;
    const int x2  = rem - r * 33;
    int gx = x0 + x2 * 2;
    if (gx > WI - 2) gx = WI - 2;    // clamp last tile's halo (values unused by valid outputs)
    const floatx2 v = *reinterpret_cast<const floatx2*>(
        x + (((n * C_IN + ci) * HI + (y0 + r)) * WI + gx));
    const int pix = r * XCOLS + x2 * 2;
    lds[pix * PSTR + ci]       = f2bf(v.x);
    lds[(pix + 1) * PSTR + ci] = f2bf(v.y);
  }
  __syncthreads();

  const int pbase  = wv * 16 + l16;   // B-fragment column n = l16
  const int px     = x0 + pbase;
  const bool valid = px < WO;

  for (int row = 0; row < RT; ++row) {
    floatx4 acc0 = {b0[0], b0[1], b0[2], b0[3]};
    floatx4 acc1 = {b1[0], b1[1], b1[2], b1[3]};
#pragma unroll
    for (int ky = 0; ky < 3; ++ky)
#pragma unroll
      for (int kx = 0; kx < 3; ++kx) {
        // B: lane holds X[ci = quad*8 + j][pixel = pbase + l16 + kx] at row row+ky
        const bf16x8 bfrag = *reinterpret_cast<const bf16x8*>(
            &lds[((row + ky) * XCOLS + pbase + kx) * PSTR + quad * 8]);
        acc0 = __builtin_amdgcn_mfma_f32_16x16x32_bf16(afrag[ky * 3 + kx][0], bfrag, acc0, 0, 0, 0);
        acc1 = __builtin_amdgcn_mfma_f32_16x16x32_bf16(afrag[ky * 3 + kx][1], bfrag, acc1, 0, 0, 0);
      }
    if (valid) {
      float* op = out + ((n * C_OUT + quad * 4) * HO + (y0 + row)) * WO + px;
#pragma unroll
      for (int r = 0; r < 4; ++r) {
        op[r * (HO * WO)]        = acc0[r];   // co = quad*4 + r
        op[(16 + r) * (HO * WO)] = acc1[r];   // co = 16 + quad*4 + r
      }
    }
  }
}

extern "C" void kernel_launch(void* const* d_in, const int* in_sizes, int n_in,
                              void* d_out, int out_size, void* d_ws, size_t ws_size,
                              hipStream_t stream) {
  const float* x    = (const float*)d_in[0];
  const float* w    = (const float*)d_in[1];
  const float* bias = (const float*)d_in[2];
  float* out        = (float*)d_out;
  dim3 grid(WI / PT, HO / RT, NI);  // 8 x 85 x 16 = 10880 blocks, 256 threads
  conv3x3_mfma<<<grid, 256, 0, stream>>>(x, w, bias, out);
}